// Round 9
// baseline (566.059 us; speedup 1.0000x reference)
//
#include <hip/hip_runtime.h>

#define BB 2048
#define EMB 128
#define NF 200
#define W_OUT 126
#define EPS 1e-5f

// ws: A-matrix f16 (800 rows x 32 taps) at offset 0 = 51200 B
// d_out[0:1024): G32 Gram scratch (memset -> stats atomics -> finalize reads),
//                fully overwritten by main afterwards.
#define AW_OFF 0

#define SPBS 4                    // stats: samples per block (wave <-> sample)
#define STATS_BLOCKS (BB / SPBS)  // 512
#define SPBM 2                    // main: samples per block (2 waves each)
#define MAIN_BLOCKS (BB / SPBM)   // 1024

typedef _Float16 half8 __attribute__((ext_vector_type(8)));
typedef float f32x4v __attribute__((ext_vector_type(4)));

__device__ __forceinline__ const float* rowptr(const int* __restrict__ xr, int r,
                                               const float* __restrict__ er,
                                               const float* __restrict__ ev) {
  if (r == 0) return ev + (size_t)xr[1] * EMB;
  if (r == 1) return er + (size_t)xr[0] * EMB;
  if (r == 2) return ev + (size_t)xr[3] * EMB;
  const int k = (r - 3) >> 1;
  return ((r - 3) & 1) ? ev + (size_t)xr[5 + 2 * k] * EMB
                       : er + (size_t)xr[4 + 2 * k] * EMB;
}

// ---------------- stats: G32 = sum_s B_s^T B_s via MFMA ---------------------
// Bm[s][x][k] = tap k of sample s at position x (k=3r+j -> h[r][x+j], k27=1),
// zeroed entirely for x >= W_OUT. G[t][t'] = sum_x Bm[x][t]*Bm[x][t'].
__global__ __launch_bounds__(256, 2) void stats_mfma(
    const int* __restrict__ xb, const float* __restrict__ er,
    const float* __restrict__ ev, float* __restrict__ gout) {
  __shared__ _Float16 Bm[SPBS][128][40];   // 40 KB
  __shared__ float Gred[SPBS][1024];       // 16 KB
  const int tid = threadIdx.x;
  const int base = blockIdx.x * SPBS;

  for (int job = tid; job < SPBS * 128; job += 256) {
    const int s = job >> 7, x = job & 127;
    _Float16* dst = &Bm[s][x][0];
    if (x < W_OUT) {
      const int* xr = xb + (size_t)(base + s) * 10;
#pragma unroll
      for (int r = 0; r < 9; r++) {
        const float* hp = rowptr(xr, r, er, ev);
        dst[3 * r + 0] = (_Float16)hp[x];
        dst[3 * r + 1] = (_Float16)hp[x + 1];
        dst[3 * r + 2] = (_Float16)hp[x + 2];
      }
      dst[27] = (_Float16)1.0f;
#pragma unroll
      for (int k = 28; k < 40; k++) dst[k] = (_Float16)0.f;
    } else {
#pragma unroll
      for (int k = 0; k < 40; k++) dst[k] = (_Float16)0.f;
    }
  }
  __syncthreads();

  const int w = tid >> 6, l = tid & 63;
  const int tl = l & 15, kl = l >> 4;
  const _Float16* __restrict__ Bf = &Bm[w][0][0];
  f32x4v a00 = {0.f,0.f,0.f,0.f}, a01 = a00, a10 = a00, a11 = a00;
#pragma unroll
  for (int c = 0; c < 4; c++) {
    const int x0 = c * 32 + kl * 8;
    half8 g0, g1;
#pragma unroll
    for (int e = 0; e < 8; e++) {         // A/B frag: idx=l&15, k=(l>>4)*8+e
      g0[e] = Bf[(x0 + e) * 40 + tl];
      g1[e] = Bf[(x0 + e) * 40 + 16 + tl];
    }
    a00 = __builtin_amdgcn_mfma_f32_16x16x32_f16(g0, g0, a00, 0, 0, 0);
    a01 = __builtin_amdgcn_mfma_f32_16x16x32_f16(g0, g1, a01, 0, 0, 0);
    a10 = __builtin_amdgcn_mfma_f32_16x16x32_f16(g1, g0, a10, 0, 0, 0);
    a11 = __builtin_amdgcn_mfma_f32_16x16x32_f16(g1, g1, a11, 0, 0, 0);
  }
  // D layout: row=(l>>4)*4+reg, col=l&15
#pragma unroll
  for (int r = 0; r < 4; r++) {
    const int rm = kl * 4 + r;
    Gred[w][rm * 32 + tl]              = a00[r];
    Gred[w][rm * 32 + 16 + tl]         = a01[r];
    Gred[w][(16 + rm) * 32 + tl]       = a10[r];
    Gred[w][(16 + rm) * 32 + 16 + tl]  = a11[r];
  }
  __syncthreads();
  for (int idx = tid; idx < 1024; idx += 256) {
    float s = Gred[0][idx] + Gred[1][idx] + Gred[2][idx] + Gred[3][idx];
    atomicAdd(&gout[idx], s);
  }
}

// ---------------- finalize: G32 -> BN params -> f16 A-matrix ----------------
__global__ __launch_bounds__(256) void finalize_kernel(
    const float* __restrict__ w1, const float* __restrict__ w2,
    const float* __restrict__ g1, const float* __restrict__ be1,
    const float* __restrict__ g2, const float* __restrict__ be2,
    const float* __restrict__ gbuf, float* __restrict__ ws) {
  __shared__ float G[1024];
  const int tid = threadIdx.x;
  for (int e = tid; e < 1024; e += 256) G[e] = gbuf[e];
  __syncthreads();
  const int f = tid;
  if (f >= NF) return;
  float w1r[9], w2r[15];
#pragma unroll
  for (int j = 0; j < 9; j++)  w1r[j] = w1[f * 9 + j];
#pragma unroll
  for (int j = 0; j < 15; j++) w2r[j] = w2[f * 15 + j];
  const float invN = 1.0f / (float)(BB * W_OUT);
  _Float16* Aw = (_Float16*)ws + AW_OFF;

  // conv1: u = w1r on taps 0..8
  float m1 = 0.f, q1 = 0.f;
#pragma unroll
  for (int i = 0; i < 9; i++) {
    m1 = fmaf(w1r[i], G[i * 32 + 27], m1);
#pragma unroll
    for (int j = 0; j < 9; j++) q1 = fmaf(w1r[i] * w1r[j], G[i * 32 + j], q1);
  }
  m1 *= invN;
  float v1 = q1 * invN - m1 * m1;
  float sc1 = g1[f] * rsqrtf(v1 + EPS);
  float sh1 = be1[f] - m1 * sc1;
  {
    _Float16* rw = Aw + (size_t)(4 * f + 0) * 32;
#pragma unroll
    for (int k = 0; k < 32; k++) rw[k] = (_Float16)0.f;
#pragma unroll
    for (int i = 0; i < 9; i++) rw[i] = (_Float16)(w1r[i] * sc1);
    rw[27] = (_Float16)sh1;
  }

  // conv2 common part
  float mcm = 0.f, qc = 0.f;
#pragma unroll
  for (int i = 0; i < 9; i++) {
    mcm = fmaf(w2r[i], G[i * 32 + 27], mcm);
#pragma unroll
    for (int j = 0; j < 9; j++) qc = fmaf(w2r[i] * w2r[j], G[i * 32 + j], qc);
  }
#pragma unroll
  for (int kk = 0; kk < 3; kk++) {
    const int a = 3 + 2 * kk, b = 4 + 2 * kk;
    float m2 = mcm, cross = 0.f, qa = 0.f, qb = 0.f, qab = 0.f;
#pragma unroll
    for (int j = 0; j < 3; j++) {
      m2 = fmaf(w2r[9 + j],  G[(3 * a + j) * 32 + 27], m2);
      m2 = fmaf(w2r[12 + j], G[(3 * b + j) * 32 + 27], m2);
    }
#pragma unroll
    for (int i = 0; i < 9; i++) {
      float t = 0.f;
#pragma unroll
      for (int j = 0; j < 3; j++) {
        t = fmaf(w2r[9 + j],  G[i * 32 + 3 * a + j], t);
        t = fmaf(w2r[12 + j], G[i * 32 + 3 * b + j], t);
      }
      cross = fmaf(w2r[i], t, cross);
    }
#pragma unroll
    for (int j = 0; j < 3; j++)
#pragma unroll
      for (int jp = 0; jp < 3; jp++) {
        qa  = fmaf(w2r[9 + j]  * w2r[9 + jp],  G[(3 * a + j) * 32 + 3 * a + jp], qa);
        qb  = fmaf(w2r[12 + j] * w2r[12 + jp], G[(3 * b + j) * 32 + 3 * b + jp], qb);
        qab = fmaf(w2r[9 + j]  * w2r[12 + jp], G[(3 * a + j) * 32 + 3 * b + jp], qab);
      }
    float q2 = qc + 2.f * cross + qa + qb + 2.f * qab;
    float mean2 = m2 * invN;
    float v2 = q2 * invN - mean2 * mean2;
    float sck = g2[f] * rsqrtf(v2 + EPS);
    float shk = be2[f] - mean2 * sck;

    _Float16* rw = Aw + (size_t)(4 * f + 1 + kk) * 32;
#pragma unroll
    for (int k = 0; k < 32; k++) rw[k] = (_Float16)0.f;
#pragma unroll
    for (int i = 0; i < 9; i++) rw[i] = (_Float16)(w2r[i] * sck);
#pragma unroll
    for (int j = 0; j < 3; j++) {
      rw[3 * a + j] = (_Float16)(w2r[9 + j]  * sck);
      rw[3 * b + j] = (_Float16)(w2r[12 + j] * sck);
    }
    rw[27] = (_Float16)shk;
  }
}

// ---------------- main: 2 samples/block, 4 waves (sample x M-half) ----------
__global__ __launch_bounds__(256, 4) void main_mfma(
    const int* __restrict__ xb, const float* __restrict__ er,
    const float* __restrict__ ev, const float* __restrict__ fcw,
    const float* __restrict__ fcb, const float* __restrict__ ws,
    float* __restrict__ out) {
  __shared__ _Float16 Bm[SPBM][128][40];   // 20 KB
  __shared__ float red[4];
  const int tid = threadIdx.x;
  const int base = blockIdx.x * SPBM;

  {  // B build: 256 jobs, one per thread
    const int s = tid >> 7, x = tid & 127;
    const int* xr = xb + (size_t)(base + s) * 10;
    const int x1 = (x + 1 < 128) ? x + 1 : 127;   // cols >= W_OUT masked by fcv
    const int x2 = (x + 2 < 128) ? x + 2 : 127;
    _Float16* dst = &Bm[s][x][0];
#pragma unroll
    for (int r = 0; r < 9; r++) {
      const float* hp = rowptr(xr, r, er, ev);
      dst[3 * r + 0] = (_Float16)hp[x];
      dst[3 * r + 1] = (_Float16)hp[x1];
      dst[3 * r + 2] = (_Float16)hp[x2];
    }
    dst[27] = (_Float16)1.0f;
#pragma unroll
    for (int k = 28; k < 40; k++) dst[k] = (_Float16)0.f;
  }
  __syncthreads();

  const int w = tid >> 6, l = tid & 63;
  const int s = w >> 1, mh = w & 1;               // sample, M-half
  const int xl = l & 15, fl = l >> 4;
  const _Float16* __restrict__ Aw = (const _Float16*)ws + AW_OFF;
  const float fcb0 = fcb[0];

  half8 bf[8];                                    // all 8 N-tiles, resident
#pragma unroll
  for (int j = 0; j < 8; j++)
    bf[j] = *(const half8*)&Bm[s][j * 16 + xl][fl * 8];

  float psum = 0.f;
#pragma unroll 2
  for (int mt = 0; mt < 25; ++mt) {
    const int mtile = mh * 25 + mt;
    const half8 af = *(const half8*)&Aw[(size_t)(mtile * 16 + xl) * 32 + fl * 8];
    const int f = mtile * 4 + fl;                 // D row=(l>>4)*4+reg = 4f+conv
    const float* __restrict__ fr = fcw + (size_t)f * W_OUT;
#pragma unroll
    for (int j = 0; j < 8; j++) {
      f32x4v acc = __builtin_amdgcn_mfma_f32_16x16x32_f16(
          af, bf[j], (f32x4v){0.f, 0.f, 0.f, 0.f}, 0, 0, 0);
      const int x = j * 16 + xl;
      const float fcv = (x < W_OUT) ? fr[x] : 0.f;
      float mv = fminf(fminf(acc[0], acc[1]), fminf(acc[2], acc[3]));
      psum = fmaf(fmaxf(mv, 0.f), fcv, psum);     // min(relu)=relu(min)
    }
  }

#pragma unroll
  for (int off = 32; off; off >>= 1) psum += __shfl_xor(psum, off, 64);
  if (l == 0) red[w] = psum;
  __syncthreads();
  if (tid < SPBM)
    out[base + tid] = red[2 * tid] + red[2 * tid + 1] + fcb0;
}

extern "C" void kernel_launch(void* const* d_in, const int* in_sizes, int n_in,
                              void* d_out, int out_size, void* d_ws, size_t ws_size,
                              hipStream_t stream) {
  const int* xb    = (const int*)d_in[0];
  const float* er  = (const float*)d_in[3];
  const float* ev  = (const float*)d_in[4];
  const float* w1  = (const float*)d_in[5];
  const float* g1  = (const float*)d_in[7];
  const float* be1 = (const float*)d_in[8];
  const float* w2  = (const float*)d_in[9];
  const float* g2  = (const float*)d_in[11];
  const float* be2 = (const float*)d_in[12];
  const float* fcw = (const float*)d_in[13];
  const float* fcb = (const float*)d_in[14];
  float* ws  = (float*)d_ws;
  float* out = (float*)d_out;

  // G32 scratch = out[0:1024) (overwritten by main afterwards)
  hipMemsetAsync(out, 0, 1024 * sizeof(float), stream);
  hipLaunchKernelGGL(stats_mfma, dim3(STATS_BLOCKS), dim3(256), 0, stream,
                     xb, er, ev, out);
  hipLaunchKernelGGL(finalize_kernel, dim3(1), dim3(256), 0, stream,
                     w1, w2, g1, be1, g2, be2, out, ws);
  hipLaunchKernelGGL(main_mfma, dim3(MAIN_BLOCKS), dim3(256), 0, stream,
                     xb, er, ev, fcw, fcb, ws, out);
}

// Round 10
// 166.808 us; speedup vs baseline: 3.3935x; 3.3935x over previous
//
#include <hip/hip_runtime.h>

#define BB 2048
#define EMB 128
#define NF 200
#define W_OUT 126
#define EPS 1e-5f

// ws: A-matrix f16 (800 rows x 32 taps) at offset 0 = 51200 B
// d_out[0:1024): G32 Gram scratch (memset -> stats atomics -> finalize),
//                fully overwritten by main afterwards.
#define AW_OFF 0

#define SPBS 4                    // stats: samples per block (wave <-> sample)
#define STATS_BLOCKS (BB / SPBS)  // 512
#define SPBM 2                    // main: samples per block (2 waves each)
#define MAIN_BLOCKS (BB / SPBM)   // 1024

typedef _Float16 half8 __attribute__((ext_vector_type(8)));
typedef float f32x4v __attribute__((ext_vector_type(4)));

__device__ __forceinline__ const float* rowptr(const int* __restrict__ xr, int r,
                                               const float* __restrict__ er,
                                               const float* __restrict__ ev) {
  if (r == 0) return ev + (size_t)xr[1] * EMB;
  if (r == 1) return er + (size_t)xr[0] * EMB;
  if (r == 2) return ev + (size_t)xr[3] * EMB;
  const int k = (r - 3) >> 1;
  return ((r - 3) & 1) ? ev + (size_t)xr[5 + 2 * k] * EMB
                       : er + (size_t)xr[4 + 2 * k] * EMB;
}

// ---------------- stats: G32 = sum_s B_s^T B_s via MFMA ---------------------
// Bt[s][k][x] = tap k at position x (k=3r+j -> h[r][x+j], k27=1), zero x>=126.
// Stride 136 halfs = 272 B: 16B-aligned b128 frag loads, benign bank pattern.
__global__ __launch_bounds__(256, 2) void stats_mfma(
    const int* __restrict__ xb, const float* __restrict__ er,
    const float* __restrict__ ev, float* __restrict__ gout) {
  __shared__ _Float16 Bt[SPBS][40][136];   // 42.5 KB
  __shared__ float Gred[SPBS][1024];       // 16 KB
  const int tid = threadIdx.x;
  const int base = blockIdx.x * SPBS;

  for (int job = tid; job < SPBS * 136; job += 256) {
    const int s = job / 136, x = job % 136;
    if (x < W_OUT) {
      const int* xr = xb + (size_t)(base + s) * 10;
#pragma unroll
      for (int r = 0; r < 9; r++) {
        const float* hp = rowptr(xr, r, er, ev);
        Bt[s][3 * r + 0][x] = (_Float16)hp[x];
        Bt[s][3 * r + 1][x] = (_Float16)hp[x + 1];
        Bt[s][3 * r + 2][x] = (_Float16)hp[x + 2];
      }
      Bt[s][27][x] = (_Float16)1.0f;
#pragma unroll
      for (int k = 28; k < 40; k++) Bt[s][k][x] = (_Float16)0.f;
    } else {
#pragma unroll
      for (int k = 0; k < 40; k++) Bt[s][k][x] = (_Float16)0.f;
    }
  }
  __syncthreads();

  const int w = tid >> 6, l = tid & 63;
  const int tl = l & 15, kl = l >> 4;
  f32x4v a00 = {0.f, 0.f, 0.f, 0.f}, a01 = a00, a10 = a00, a11 = a00;
#pragma unroll
  for (int c = 0; c < 4; c++) {
    const int x0 = c * 32 + kl * 8;
    const half8 g0 = *(const half8*)&Bt[w][tl][x0];       // taps 0..15
    const half8 g1 = *(const half8*)&Bt[w][16 + tl][x0];  // taps 16..31
    a00 = __builtin_amdgcn_mfma_f32_16x16x32_f16(g0, g0, a00, 0, 0, 0);
    a01 = __builtin_amdgcn_mfma_f32_16x16x32_f16(g0, g1, a01, 0, 0, 0);
    a10 = __builtin_amdgcn_mfma_f32_16x16x32_f16(g1, g0, a10, 0, 0, 0);
    a11 = __builtin_amdgcn_mfma_f32_16x16x32_f16(g1, g1, a11, 0, 0, 0);
  }
  // D layout: row=(l>>4)*4+reg, col=l&15
#pragma unroll
  for (int r = 0; r < 4; r++) {
    const int rm = kl * 4 + r;
    Gred[w][rm * 32 + tl]             = a00[r];
    Gred[w][rm * 32 + 16 + tl]        = a01[r];
    Gred[w][(16 + rm) * 32 + tl]      = a10[r];
    Gred[w][(16 + rm) * 32 + 16 + tl] = a11[r];
  }
  __syncthreads();
  for (int idx = tid; idx < 1024; idx += 256) {
    float s = Gred[0][idx] + Gred[1][idx] + Gred[2][idx] + Gred[3][idx];
    atomicAdd(&gout[idx], s);
  }
}

// ---------------- finalize: G32 -> BN params -> f16 A-matrix ----------------
__global__ __launch_bounds__(256) void finalize_kernel(
    const float* __restrict__ w1, const float* __restrict__ w2,
    const float* __restrict__ g1, const float* __restrict__ be1,
    const float* __restrict__ g2, const float* __restrict__ be2,
    const float* __restrict__ gbuf, float* __restrict__ ws) {
  __shared__ float G[1024];
  const int tid = threadIdx.x;
  for (int e = tid; e < 1024; e += 256) G[e] = gbuf[e];
  __syncthreads();
  const int f = tid;
  if (f >= NF) return;
  float w1r[9], w2r[15];
#pragma unroll
  for (int j = 0; j < 9; j++)  w1r[j] = w1[f * 9 + j];
#pragma unroll
  for (int j = 0; j < 15; j++) w2r[j] = w2[f * 15 + j];
  const float invN = 1.0f / (float)(BB * W_OUT);
  _Float16* Aw = (_Float16*)ws + AW_OFF;

  float m1 = 0.f, q1 = 0.f;
#pragma unroll
  for (int i = 0; i < 9; i++) {
    m1 = fmaf(w1r[i], G[i * 32 + 27], m1);
#pragma unroll
    for (int j = 0; j < 9; j++) q1 = fmaf(w1r[i] * w1r[j], G[i * 32 + j], q1);
  }
  m1 *= invN;
  float v1 = q1 * invN - m1 * m1;
  float sc1 = g1[f] * rsqrtf(v1 + EPS);
  float sh1 = be1[f] - m1 * sc1;
  {
    _Float16* rw = Aw + (size_t)(4 * f + 0) * 32;
#pragma unroll
    for (int k = 0; k < 32; k++) rw[k] = (_Float16)0.f;
#pragma unroll
    for (int i = 0; i < 9; i++) rw[i] = (_Float16)(w1r[i] * sc1);
    rw[27] = (_Float16)sh1;
  }

  float mcm = 0.f, qc = 0.f;
#pragma unroll
  for (int i = 0; i < 9; i++) {
    mcm = fmaf(w2r[i], G[i * 32 + 27], mcm);
#pragma unroll
    for (int j = 0; j < 9; j++) qc = fmaf(w2r[i] * w2r[j], G[i * 32 + j], qc);
  }
#pragma unroll
  for (int kk = 0; kk < 3; kk++) {
    const int a = 3 + 2 * kk, b = 4 + 2 * kk;
    float m2 = mcm, cross = 0.f, qa = 0.f, qb = 0.f, qab = 0.f;
#pragma unroll
    for (int j = 0; j < 3; j++) {
      m2 = fmaf(w2r[9 + j],  G[(3 * a + j) * 32 + 27], m2);
      m2 = fmaf(w2r[12 + j], G[(3 * b + j) * 32 + 27], m2);
    }
#pragma unroll
    for (int i = 0; i < 9; i++) {
      float t = 0.f;
#pragma unroll
      for (int j = 0; j < 3; j++) {
        t = fmaf(w2r[9 + j],  G[i * 32 + 3 * a + j], t);
        t = fmaf(w2r[12 + j], G[i * 32 + 3 * b + j], t);
      }
      cross = fmaf(w2r[i], t, cross);
    }
#pragma unroll
    for (int j = 0; j < 3; j++)
#pragma unroll
      for (int jp = 0; jp < 3; jp++) {
        qa  = fmaf(w2r[9 + j]  * w2r[9 + jp],  G[(3 * a + j) * 32 + 3 * a + jp], qa);
        qb  = fmaf(w2r[12 + j] * w2r[12 + jp], G[(3 * b + j) * 32 + 3 * b + jp], qb);
        qab = fmaf(w2r[9 + j]  * w2r[12 + jp], G[(3 * a + j) * 32 + 3 * b + jp], qab);
      }
    float q2 = qc + 2.f * cross + qa + qb + 2.f * qab;
    float mean2 = m2 * invN;
    float v2 = q2 * invN - mean2 * mean2;
    float sck = g2[f] * rsqrtf(v2 + EPS);
    float shk = be2[f] - mean2 * sck;

    _Float16* rw = Aw + (size_t)(4 * f + 1 + kk) * 32;
#pragma unroll
    for (int k = 0; k < 32; k++) rw[k] = (_Float16)0.f;
#pragma unroll
    for (int i = 0; i < 9; i++) rw[i] = (_Float16)(w2r[i] * sck);
#pragma unroll
    for (int j = 0; j < 3; j++) {
      rw[3 * a + j] = (_Float16)(w2r[9 + j]  * sck);
      rw[3 * b + j] = (_Float16)(w2r[12 + j] * sck);
    }
    rw[27] = (_Float16)shk;
  }
}

// ---------------- main: j outer / mt inner, minimal live state --------------
__global__ __launch_bounds__(256, 6) void main_mfma(
    const int* __restrict__ xb, const float* __restrict__ er,
    const float* __restrict__ ev, const float* __restrict__ fcw,
    const float* __restrict__ fcb, const float* __restrict__ ws,
    float* __restrict__ out) {
  __shared__ _Float16 Bm[SPBM][128][40];   // 20 KB
  __shared__ float red[4];
  const int tid = threadIdx.x;
  const int base = blockIdx.x * SPBM;

  {  // B build: 256 jobs, one per thread
    const int s = tid >> 7, x = tid & 127;
    const int* xr = xb + (size_t)(base + s) * 10;
    const int x1 = (x + 1 < 128) ? x + 1 : 127;   // cols >= W_OUT masked by fcv
    const int x2 = (x + 2 < 128) ? x + 2 : 127;
    _Float16* dst = &Bm[s][x][0];
#pragma unroll
    for (int r = 0; r < 9; r++) {
      const float* hp = rowptr(xr, r, er, ev);
      dst[3 * r + 0] = (_Float16)hp[x];
      dst[3 * r + 1] = (_Float16)hp[x1];
      dst[3 * r + 2] = (_Float16)hp[x2];
    }
    dst[27] = (_Float16)1.0f;
#pragma unroll
    for (int k = 28; k < 40; k++) dst[k] = (_Float16)0.f;
  }
  __syncthreads();

  const int w = tid >> 6, l = tid & 63;
  const int s = w >> 1, mh = w & 1;               // sample, M-half
  const int xl = l & 15, fl = l >> 4;
  const _Float16* __restrict__ Aw = (const _Float16*)ws + AW_OFF;
  const float fcb0 = fcb[0];

  float psum = 0.f;
#pragma unroll 1
  for (int j = 0; j < 8; ++j) {
    const half8 bfj = *(const half8*)&Bm[s][j * 16 + xl][fl * 8];
    const int x = j * 16 + xl;
    const bool xv = (x < W_OUT);
    const int xi = xv ? x : 0;                    // clamp: no OOB on fcw
#pragma unroll 2
    for (int mt = 0; mt < 25; ++mt) {
      const int mtile = mh * 25 + mt;
      const half8 af = *(const half8*)&Aw[(size_t)(mtile * 16 + xl) * 32 + fl * 8];
      const int f = mtile * 4 + fl;               // D row=(l>>4)*4+reg = 4f+conv
      f32x4v acc = __builtin_amdgcn_mfma_f32_16x16x32_f16(
          af, bfj, (f32x4v){0.f, 0.f, 0.f, 0.f}, 0, 0, 0);
      const float fcl = fcw[(size_t)f * W_OUT + xi];
      const float fcv = xv ? fcl : 0.f;
      float mv = fminf(fminf(acc[0], acc[1]), fminf(acc[2], acc[3]));
      psum = fmaf(fmaxf(mv, 0.f), fcv, psum);     // min(relu)=relu(min)
    }
  }

#pragma unroll
  for (int off = 32; off; off >>= 1) psum += __shfl_xor(psum, off, 64);
  if (l == 0) red[w] = psum;
  __syncthreads();
  if (tid < SPBM)
    out[base + tid] = red[2 * tid] + red[2 * tid + 1] + fcb0;
}

extern "C" void kernel_launch(void* const* d_in, const int* in_sizes, int n_in,
                              void* d_out, int out_size, void* d_ws, size_t ws_size,
                              hipStream_t stream) {
  const int* xb    = (const int*)d_in[0];
  const float* er  = (const float*)d_in[3];
  const float* ev  = (const float*)d_in[4];
  const float* w1  = (const float*)d_in[5];
  const float* g1  = (const float*)d_in[7];
  const float* be1 = (const float*)d_in[8];
  const float* w2  = (const float*)d_in[9];
  const float* g2  = (const float*)d_in[11];
  const float* be2 = (const float*)d_in[12];
  const float* fcw = (const float*)d_in[13];
  const float* fcb = (const float*)d_in[14];
  float* ws  = (float*)d_ws;
  float* out = (float*)d_out;

  // G32 scratch = out[0:1024) (overwritten by main afterwards)
  hipMemsetAsync(out, 0, 1024 * sizeof(float), stream);
  hipLaunchKernelGGL(stats_mfma, dim3(STATS_BLOCKS), dim3(256), 0, stream,
                     xb, er, ev, out);
  hipLaunchKernelGGL(finalize_kernel, dim3(1), dim3(256), 0, stream,
                     w1, w2, g1, be1, g2, be2, out, ws);
  hipLaunchKernelGGL(main_mfma, dim3(MAIN_BLOCKS), dim3(256), 0, stream,
                     xb, er, ev, fcw, fcb, ws, out);
}

// Round 11
// 57.942 us; speedup vs baseline: 9.7693x; 2.8789x over previous
//
#include <hip/hip_runtime.h>

#define BB 2048
#define EMB 128
#define NF 200
#define W_OUT 126
#define EPS 1e-5f

// ws: A-matrix f16 (800 rows x 32 taps) at offset 0 = 51200 B
// d_out[0:1024): G32 Gram scratch (memset -> stats atomics -> finalize),
//                fully overwritten by main afterwards.
#define AW_OFF 0

#define SPBS 4                    // stats: samples per block (wave <-> sample)
#define STATS_BLOCKS (BB / SPBS)  // 512
#define SPBM 2                    // main: samples per block (2 waves each)
#define MAIN_BLOCKS (BB / SPBM)   // 1024

typedef _Float16 half8 __attribute__((ext_vector_type(8)));
typedef float f32x4v __attribute__((ext_vector_type(4)));

__device__ __forceinline__ const float* rowptr(const int* __restrict__ xr, int r,
                                               const float* __restrict__ er,
                                               const float* __restrict__ ev) {
  if (r == 0) return ev + (size_t)xr[1] * EMB;
  if (r == 1) return er + (size_t)xr[0] * EMB;
  if (r == 2) return ev + (size_t)xr[3] * EMB;
  const int k = (r - 3) >> 1;
  return ((r - 3) & 1) ? ev + (size_t)xr[5 + 2 * k] * EMB
                       : er + (size_t)xr[4 + 2 * k] * EMB;
}

// ---------------- stats: G32 = sum_s B_s^T B_s via MFMA (R10, proven) -------
__global__ __launch_bounds__(256, 2) void stats_mfma(
    const int* __restrict__ xb, const float* __restrict__ er,
    const float* __restrict__ ev, float* __restrict__ gout) {
  __shared__ _Float16 Bt[SPBS][40][136];   // 42.5 KB
  __shared__ float Gred[SPBS][1024];       // 16 KB
  const int tid = threadIdx.x;
  const int base = blockIdx.x * SPBS;

  for (int job = tid; job < SPBS * 136; job += 256) {
    const int s = job / 136, x = job % 136;
    if (x < W_OUT) {
      const int* xr = xb + (size_t)(base + s) * 10;
#pragma unroll
      for (int r = 0; r < 9; r++) {
        const float* hp = rowptr(xr, r, er, ev);
        Bt[s][3 * r + 0][x] = (_Float16)hp[x];
        Bt[s][3 * r + 1][x] = (_Float16)hp[x + 1];
        Bt[s][3 * r + 2][x] = (_Float16)hp[x + 2];
      }
      Bt[s][27][x] = (_Float16)1.0f;
#pragma unroll
      for (int k = 28; k < 40; k++) Bt[s][k][x] = (_Float16)0.f;
    } else {
#pragma unroll
      for (int k = 0; k < 40; k++) Bt[s][k][x] = (_Float16)0.f;
    }
  }
  __syncthreads();

  const int w = tid >> 6, l = tid & 63;
  const int tl = l & 15, kl = l >> 4;
  f32x4v a00 = {0.f, 0.f, 0.f, 0.f}, a01 = a00, a10 = a00, a11 = a00;
#pragma unroll
  for (int c = 0; c < 4; c++) {
    const int x0 = c * 32 + kl * 8;
    const half8 g0 = *(const half8*)&Bt[w][tl][x0];       // taps 0..15
    const half8 g1 = *(const half8*)&Bt[w][16 + tl][x0];  // taps 16..31
    a00 = __builtin_amdgcn_mfma_f32_16x16x32_f16(g0, g0, a00, 0, 0, 0);
    a01 = __builtin_amdgcn_mfma_f32_16x16x32_f16(g0, g1, a01, 0, 0, 0);
    a10 = __builtin_amdgcn_mfma_f32_16x16x32_f16(g1, g0, a10, 0, 0, 0);
    a11 = __builtin_amdgcn_mfma_f32_16x16x32_f16(g1, g1, a11, 0, 0, 0);
  }
  // D layout: row=(l>>4)*4+reg, col=l&15
#pragma unroll
  for (int r = 0; r < 4; r++) {
    const int rm = kl * 4 + r;
    Gred[w][rm * 32 + tl]             = a00[r];
    Gred[w][rm * 32 + 16 + tl]        = a01[r];
    Gred[w][(16 + rm) * 32 + tl]      = a10[r];
    Gred[w][(16 + rm) * 32 + 16 + tl] = a11[r];
  }
  __syncthreads();
  for (int idx = tid; idx < 1024; idx += 256) {
    float s = Gred[0][idx] + Gred[1][idx] + Gred[2][idx] + Gred[3][idx];
    atomicAdd(&gout[idx], s);
  }
}

// ---------------- finalize: G32 -> BN params -> f16 A-matrix (R10) ----------
__global__ __launch_bounds__(256) void finalize_kernel(
    const float* __restrict__ w1, const float* __restrict__ w2,
    const float* __restrict__ g1, const float* __restrict__ be1,
    const float* __restrict__ g2, const float* __restrict__ be2,
    const float* __restrict__ gbuf, float* __restrict__ ws) {
  __shared__ float G[1024];
  const int tid = threadIdx.x;
  for (int e = tid; e < 1024; e += 256) G[e] = gbuf[e];
  __syncthreads();
  const int f = tid;
  if (f >= NF) return;
  float w1r[9], w2r[15];
#pragma unroll
  for (int j = 0; j < 9; j++)  w1r[j] = w1[f * 9 + j];
#pragma unroll
  for (int j = 0; j < 15; j++) w2r[j] = w2[f * 15 + j];
  const float invN = 1.0f / (float)(BB * W_OUT);
  _Float16* Aw = (_Float16*)ws + AW_OFF;

  float m1 = 0.f, q1 = 0.f;
#pragma unroll
  for (int i = 0; i < 9; i++) {
    m1 = fmaf(w1r[i], G[i * 32 + 27], m1);
#pragma unroll
    for (int j = 0; j < 9; j++) q1 = fmaf(w1r[i] * w1r[j], G[i * 32 + j], q1);
  }
  m1 *= invN;
  float v1 = q1 * invN - m1 * m1;
  float sc1 = g1[f] * rsqrtf(v1 + EPS);
  float sh1 = be1[f] - m1 * sc1;
  {
    _Float16* rw = Aw + (size_t)(4 * f + 0) * 32;
#pragma unroll
    for (int k = 0; k < 32; k++) rw[k] = (_Float16)0.f;
#pragma unroll
    for (int i = 0; i < 9; i++) rw[i] = (_Float16)(w1r[i] * sc1);
    rw[27] = (_Float16)sh1;
  }

  float mcm = 0.f, qc = 0.f;
#pragma unroll
  for (int i = 0; i < 9; i++) {
    mcm = fmaf(w2r[i], G[i * 32 + 27], mcm);
#pragma unroll
    for (int j = 0; j < 9; j++) qc = fmaf(w2r[i] * w2r[j], G[i * 32 + j], qc);
  }
#pragma unroll
  for (int kk = 0; kk < 3; kk++) {
    const int a = 3 + 2 * kk, b = 4 + 2 * kk;
    float m2 = mcm, cross = 0.f, qa = 0.f, qb = 0.f, qab = 0.f;
#pragma unroll
    for (int j = 0; j < 3; j++) {
      m2 = fmaf(w2r[9 + j],  G[(3 * a + j) * 32 + 27], m2);
      m2 = fmaf(w2r[12 + j], G[(3 * b + j) * 32 + 27], m2);
    }
#pragma unroll
    for (int i = 0; i < 9; i++) {
      float t = 0.f;
#pragma unroll
      for (int j = 0; j < 3; j++) {
        t = fmaf(w2r[9 + j],  G[i * 32 + 3 * a + j], t);
        t = fmaf(w2r[12 + j], G[i * 32 + 3 * b + j], t);
      }
      cross = fmaf(w2r[i], t, cross);
    }
#pragma unroll
    for (int j = 0; j < 3; j++)
#pragma unroll
      for (int jp = 0; jp < 3; jp++) {
        qa  = fmaf(w2r[9 + j]  * w2r[9 + jp],  G[(3 * a + j) * 32 + 3 * a + jp], qa);
        qb  = fmaf(w2r[12 + j] * w2r[12 + jp], G[(3 * b + j) * 32 + 3 * b + jp], qb);
        qab = fmaf(w2r[9 + j]  * w2r[12 + jp], G[(3 * a + j) * 32 + 3 * b + jp], qab);
      }
    float q2 = qc + 2.f * cross + qa + qb + 2.f * qab;
    float mean2 = m2 * invN;
    float v2 = q2 * invN - mean2 * mean2;
    float sck = g2[f] * rsqrtf(v2 + EPS);
    float shk = be2[f] - mean2 * sck;

    _Float16* rw = Aw + (size_t)(4 * f + 1 + kk) * 32;
#pragma unroll
    for (int k = 0; k < 32; k++) rw[k] = (_Float16)0.f;
#pragma unroll
    for (int i = 0; i < 9; i++) rw[i] = (_Float16)(w2r[i] * sck);
#pragma unroll
    for (int j = 0; j < 3; j++) {
      rw[3 * a + j] = (_Float16)(w2r[9 + j]  * sck);
      rw[3 * b + j] = (_Float16)(w2r[12 + j] * sck);
    }
    rw[27] = (_Float16)shk;
  }
}

// ---------------- main: R8 register-blocked loop nest, M-half wave split ----
__global__ __launch_bounds__(256, 4) void main_mfma(
    const int* __restrict__ xb, const float* __restrict__ er,
    const float* __restrict__ ev, const float* __restrict__ fcw,
    const float* __restrict__ fcb, const float* __restrict__ ws,
    float* __restrict__ out) {
  __shared__ _Float16 Bm[SPBM][128][40];   // 20 KB
  __shared__ float red[4];
  const int tid = threadIdx.x;
  const int base = blockIdx.x * SPBM;

  {  // B build: 256 jobs, one per thread
    const int s = tid >> 7, x = tid & 127;
    const int* xr = xb + (size_t)(base + s) * 10;
    const int x1 = (x + 1 < 128) ? x + 1 : 127;   // cols >= W_OUT masked by fcv
    const int x2 = (x + 2 < 128) ? x + 2 : 127;
    _Float16* dst = &Bm[s][x][0];
#pragma unroll
    for (int r = 0; r < 9; r++) {
      const float* hp = rowptr(xr, r, er, ev);
      dst[3 * r + 0] = (_Float16)hp[x];
      dst[3 * r + 1] = (_Float16)hp[x1];
      dst[3 * r + 2] = (_Float16)hp[x2];
    }
    dst[27] = (_Float16)1.0f;
#pragma unroll
    for (int k = 28; k < 40; k++) dst[k] = (_Float16)0.f;
  }
  __syncthreads();

  const int w = tid >> 6, l = tid & 63;
  const int s = w >> 1, mh = w & 1;               // sample, M-half
  const int xl = l & 15, fl = l >> 4;
  const _Float16* __restrict__ Aw = (const _Float16*)ws + AW_OFF;
  const float fcb0 = fcb[0];

  float psum = 0.f;
#pragma unroll 1
  for (int ntb = 0; ntb < 2; ++ntb) {
    half8 bf[4];
#pragma unroll
    for (int j = 0; j < 4; ++j)                   // 4 N-tiles resident
      bf[j] = *(const half8*)&Bm[s][(ntb * 4 + j) * 16 + xl][fl * 8];
#pragma unroll 1
    for (int mtb = 0; mtb < 5; ++mtb) {
      half8 af[5];
#pragma unroll
      for (int i = 0; i < 5; ++i) {               // 5 M-tiles per batch
        const int mtile = mh * 25 + mtb * 5 + i;
        af[i] = *(const half8*)&Aw[(size_t)(mtile * 16 + xl) * 32 + fl * 8];
      }
#pragma unroll
      for (int i = 0; i < 5; ++i) {
        const int f = (mh * 25 + mtb * 5 + i) * 4 + fl;  // D row=(l>>4)*4+reg
#pragma unroll
        for (int j = 0; j < 4; ++j) {
          f32x4v acc = __builtin_amdgcn_mfma_f32_16x16x32_f16(
              af[i], bf[j], (f32x4v){0.f, 0.f, 0.f, 0.f}, 0, 0, 0);
          const int x = (ntb * 4 + j) * 16 + xl;
          const bool xv = (x < W_OUT);
          const float fcl = fcw[(size_t)f * W_OUT + (xv ? x : 0)];
          const float fcv = xv ? fcl : 0.f;
          float mv = fminf(fminf(acc[0], acc[1]), fminf(acc[2], acc[3]));
          psum = fmaf(fmaxf(mv, 0.f), fcv, psum); // min(relu)=relu(min)
        }
      }
    }
  }

#pragma unroll
  for (int off = 32; off; off >>= 1) psum += __shfl_xor(psum, off, 64);
  if (l == 0) red[w] = psum;
  __syncthreads();
  if (tid < SPBM)
    out[base + tid] = red[2 * tid] + red[2 * tid + 1] + fcb0;
}

extern "C" void kernel_launch(void* const* d_in, const int* in_sizes, int n_in,
                              void* d_out, int out_size, void* d_ws, size_t ws_size,
                              hipStream_t stream) {
  const int* xb    = (const int*)d_in[0];
  const float* er  = (const float*)d_in[3];
  const float* ev  = (const float*)d_in[4];
  const float* w1  = (const float*)d_in[5];
  const float* g1  = (const float*)d_in[7];
  const float* be1 = (const float*)d_in[8];
  const float* w2  = (const float*)d_in[9];
  const float* g2  = (const float*)d_in[11];
  const float* be2 = (const float*)d_in[12];
  const float* fcw = (const float*)d_in[13];
  const float* fcb = (const float*)d_in[14];
  float* ws  = (float*)d_ws;
  float* out = (float*)d_out;

  // G32 scratch = out[0:1024) (overwritten by main afterwards)
  hipMemsetAsync(out, 0, 1024 * sizeof(float), stream);
  hipLaunchKernelGGL(stats_mfma, dim3(STATS_BLOCKS), dim3(256), 0, stream,
                     xb, er, ev, out);
  hipLaunchKernelGGL(finalize_kernel, dim3(1), dim3(256), 0, stream,
                     w1, w2, g1, be1, g2, be2, out, ws);
  hipLaunchKernelGGL(main_mfma, dim3(MAIN_BLOCKS), dim3(256), 0, stream,
                     xb, er, ev, fcw, fcb, ws, out);
}